// Round 4
// baseline (148.683 us; speedup 1.0000x reference)
//
#include <hip/hip_runtime.h>

// Problem constants (fixed by the reference file).
#define T_LEN 8192
#define D_CH  2048
#define CC    128                 // chunks along T
#define L_C   (T_LEN / CC)        // 64 steps per chunk

// v = z*v + x (x real), z complex.
__device__ __forceinline__ void step_real(float zre, float zim,
                                          float& vre, float& vim, float x) {
    float nre = fmaf(zre, vre, fmaf(-zim, vim, x));
    float nim = fmaf(zre, vim, zim * vre);
    vre = nre; vim = nim;
}

__device__ __forceinline__ void load_z(const float* __restrict__ size_,
                                       const float* __restrict__ theta_,
                                       int d, float& zre, float& zim) {
    float e = expf(size_[d]);
    float r = expf(-e);
    float s, c;
    sincosf(theta_[d], &s, &c);
    zre = r * c;
    zim = r * s;
}

// Pass 1: per (chunk, channel) local scan from v=0. Streams the UNSEEDED local
// values straight into d_out (x is read from HBM exactly once per bench call),
// and publishes the chunk-final complex value to ws.
template <bool ILV>
__global__ __launch_bounds__(256, 4) void k_local(const float* __restrict__ x,
                                                  const float* __restrict__ size_,
                                                  const float* __restrict__ theta_,
                                                  float* __restrict__ out,
                                                  float2* __restrict__ ws) {
    const int d = blockIdx.x * 256 + threadIdx.x;
    const int c = blockIdx.y;
    float zre, zim;
    load_z(size_, theta_, d, zre, zim);

    const float* xp = x + (size_t)c * L_C * D_CH + d;
    float vre = 0.f, vim = 0.f;
    if (ILV) {
        float2* o2 = (float2*)out + (size_t)c * L_C * D_CH + d;
#pragma unroll 16
        for (int k = 0; k < L_C; ++k) {
            float xv = xp[(size_t)k * D_CH];
            step_real(zre, zim, vre, vim, xv);
            o2[(size_t)k * D_CH] = make_float2(vre, vim);
        }
    } else {
        float* o = out + (size_t)c * L_C * D_CH + d;
#pragma unroll 16
        for (int k = 0; k < L_C; ++k) {
            float xv = xp[(size_t)k * D_CH];
            step_real(zre, zim, vre, vim, xv);
            o[(size_t)k * D_CH] = vre;
        }
    }
    ws[c * D_CH + d] = make_float2(vre, vim);
}

// Pass 2: per-channel exclusive scan over the CC chunk sums with z^L (closed
// form). In-place: ws[c][d] := carry INTO chunk c.
__global__ __launch_bounds__(256) void k_carry(const float* __restrict__ size_,
                                               const float* __restrict__ theta_,
                                               float2* __restrict__ ws) {
    const int d = blockIdx.x * 256 + threadIdx.x;
    float e  = expf(size_[d]);
    float th = theta_[d];
    float rL = expf(-(float)L_C * e);          // underflow->0 is correct
    float sL, cL;
    sincosf((float)L_C * th, &sL, &cL);
    const float zLre = rL * cL, zLim = rL * sL;

    float cre = 0.f, cim = 0.f;
    for (int base = 0; base < CC; base += 16) {
        float2 loc[16];
#pragma unroll
        for (int j = 0; j < 16; ++j)
            loc[j] = ws[(base + j) * D_CH + d];    // batch-issued loads
#pragma unroll
        for (int j = 0; j < 16; ++j) {
            ws[(base + j) * D_CH + d] = make_float2(cre, cim);
            float nre = fmaf(zLre, cre, fmaf(-zLim, cim, loc[j].x));
            float nim = fmaf(zLre, cim, fmaf(zLim, cre, loc[j].y));
            cre = nre; cim = nim;
        }
    }
}

// Pass 3: streaming elementwise fixup. out[t,d] = local[t,d] + carry_c * z^(k+1),
// k = t - c*L. No serial dependence on memory: 16 rows per thread, w-recurrence
// in registers from a closed-form start. Reads of d_out are L3-hot.
template <bool ILV>
__global__ __launch_bounds__(256, 4) void k_fix(const float* __restrict__ size_,
                                                const float* __restrict__ theta_,
                                                const float2* __restrict__ carry,
                                                float* __restrict__ out) {
    const int d  = blockIdx.x * 256 + threadIdx.x;
    const int t0 = blockIdx.y * 16;
    const int c  = t0 / L_C;                  // 16 | 64, rows stay in one chunk
    const int k0 = t0 % L_C;

    float e  = expf(size_[d]);
    float th = theta_[d];
    float s, cs;
    // z itself
    float r1 = expf(-e);
    sincosf(th, &s, &cs);
    const float zre = r1 * cs, zim = r1 * s;
    // w = z^(k0+1), closed form
    float p  = (float)(k0 + 1);
    float rp = expf(-p * e);
    sincosf(p * th, &s, &cs);
    float wre = rp * cs, wim = rp * s;

    const float2 cv = carry[c * D_CH + d];

    if (ILV) {
        float2* o2 = (float2*)out + (size_t)t0 * D_CH + d;
        float2 loc[16];
#pragma unroll
        for (int j = 0; j < 16; ++j) loc[j] = o2[(size_t)j * D_CH];
#pragma unroll
        for (int j = 0; j < 16; ++j) {
            float re = fmaf(wre, cv.x, fmaf(-wim, cv.y, loc[j].x));
            float im = fmaf(wre, cv.y, fmaf( wim, cv.x, loc[j].y));
            o2[(size_t)j * D_CH] = make_float2(re, im);
            float nwre = wre * zre - wim * zim;
            float nwim = fmaf(wre, zim, wim * zre);
            wre = nwre; wim = nwim;
        }
    } else {
        float* o = out + (size_t)t0 * D_CH + d;
        float loc[16];
#pragma unroll
        for (int j = 0; j < 16; ++j) loc[j] = o[(size_t)j * D_CH];
#pragma unroll
        for (int j = 0; j < 16; ++j) {
            o[(size_t)j * D_CH] = fmaf(wre, cv.x, fmaf(-wim, cv.y, loc[j]));
            float nwre = wre * zre - wim * zim;
            float nwim = fmaf(wre, zim, wim * zre);
            wre = nwre; wim = nwim;
        }
    }
}

extern "C" void kernel_launch(void* const* d_in, const int* in_sizes, int n_in,
                              void* d_out, int out_size, void* d_ws, size_t ws_size,
                              hipStream_t stream) {
    const float* x  = (const float*)d_in[0];
    const float* sz = (const float*)d_in[1];
    const float* th = (const float*)d_in[2];
    float2* ws = (float2*)d_ws;                   // CC * D_CH * 8 B = 2 MB
    float* out = (float*)d_out;
    const bool realOnly = (out_size == T_LEN * D_CH);

    dim3 blk(256);
    dim3 gridL(D_CH / 256, CC);                   // 1024 blocks = 4/CU
    dim3 gridF(D_CH / 256, T_LEN / 16);           // 8 x 512 blocks

    if (realOnly) {
        k_local<false><<<gridL, blk, 0, stream>>>(x, sz, th, out, ws);
        k_carry<<<dim3(D_CH / 256), blk, 0, stream>>>(sz, th, ws);
        k_fix<false><<<gridF, blk, 0, stream>>>(sz, th, ws, out);
    } else {
        k_local<true><<<gridL, blk, 0, stream>>>(x, sz, th, out, ws);
        k_carry<<<dim3(D_CH / 256), blk, 0, stream>>>(sz, th, ws);
        k_fix<true><<<gridF, blk, 0, stream>>>(sz, th, ws, out);
    }
}

// Round 7
// 128.437 us; speedup vs baseline: 1.1576x; 1.1576x over previous
//
#include <hip/hip_runtime.h>

// Problem constants (fixed by the reference file).
#define T_LEN 8192
#define D_CH  2048
#define CC    128                 // chunks along T
#define L_C   (T_LEN / CC)        // 64 steps per chunk

// v = z*v + x (x real), z complex.
__device__ __forceinline__ void step_real(float zre, float zim,
                                          float& vre, float& vim, float x) {
    float nre = fmaf(zre, vre, fmaf(-zim, vim, x));
    float nim = fmaf(zre, vim, zim * vre);
    vre = nre; vim = nim;
}

__device__ __forceinline__ void load_z(const float* __restrict__ size_,
                                       const float* __restrict__ theta_,
                                       int d, float& zre, float& zim) {
    float e = expf(size_[d]);
    float r = expf(-e);
    float s, c;
    sincosf(theta_[d], &s, &c);
    zre = r * c;
    zim = r * s;
}

// Kernel 1: per (chunk, channel) local scan from v=0; publish ONLY the
// chunk-final complex value. Pure 64 MB coalesced read -> BW floor.
__global__ __launch_bounds__(256) void k_sums(const float* __restrict__ x,
                                              const float* __restrict__ size_,
                                              const float* __restrict__ theta_,
                                              float2* __restrict__ sums) {
    const int d = blockIdx.x * 256 + threadIdx.x;
    const int c = blockIdx.y;
    float zre, zim;
    load_z(size_, theta_, d, zre, zim);

    const float* xp = x + (size_t)c * L_C * D_CH + d;
    float vre = 0.f, vim = 0.f;
#pragma unroll 16
    for (int k = 0; k < L_C; ++k)
        step_real(zre, zim, vre, vim, xp[(size_t)k * D_CH]);
    sums[c * D_CH + d] = make_float2(vre, vim);
}

// Kernel 2: block (c) recomputes its own carry prefix over sums[0..c-1]
// (tiny, L2/L3-resident, batched 16-deep, block-uniform predication), then
// scans its chunk seeded with the carry, re-reading x (L3-warm from k1) and
// streaming the output with nontemporal stores.
template <bool ILV>
__global__ __launch_bounds__(256) void k_scan(const float* __restrict__ x,
                                              const float* __restrict__ size_,
                                              const float* __restrict__ theta_,
                                              const float2* __restrict__ sums,
                                              float* __restrict__ out) {
    const int d = blockIdx.x * 256 + threadIdx.x;
    const int c = blockIdx.y;

    float zre, zim;
    load_z(size_, theta_, d, zre, zim);

    // z^L closed form (underflow of rL -> 0 is correct).
    float e  = expf(size_[d]);
    float rL = expf(-(float)L_C * e);
    float sL, cL;
    sincosf((float)L_C * theta_[d], &sL, &cL);
    const float zLre = rL * cL, zLim = rL * sL;

    // Carry into chunk c: iterate carry = zL*carry + sums[j], j = 0..c-1.
    float cre = 0.f, cim = 0.f;
    for (int base = 0; base < c; base += 16) {        // c is block-uniform
        float2 loc[16];
#pragma unroll
        for (int j = 0; j < 16; ++j)
            loc[j] = (base + j < c) ? sums[(base + j) * D_CH + d]
                                    : make_float2(0.f, 0.f);
#pragma unroll
        for (int j = 0; j < 16; ++j) {
            if (base + j < c) {                        // block-uniform branch
                float nre = fmaf(zLre, cre, fmaf(-zLim, cim, loc[j].x));
                float nim = fmaf(zLre, cim, fmaf(zLim, cre, loc[j].y));
                cre = nre; cim = nim;
            }
        }
    }

    // Scan the chunk seeded with the carry; stream out (nontemporal).
    float vre = cre, vim = cim;
    const float* xp = x + (size_t)c * L_C * D_CH + d;
    if (ILV) {
        float2* o2 = (float2*)out + (size_t)c * L_C * D_CH + d;
#pragma unroll 16
        for (int k = 0; k < L_C; ++k) {
            step_real(zre, zim, vre, vim, xp[(size_t)k * D_CH]);
            float2 v = make_float2(vre, vim);
            __builtin_nontemporal_store(v.x, &o2[(size_t)k * D_CH].x);
            __builtin_nontemporal_store(v.y, &o2[(size_t)k * D_CH].y);
        }
    } else {
        float* o = out + (size_t)c * L_C * D_CH + d;
#pragma unroll 16
        for (int k = 0; k < L_C; ++k) {
            step_real(zre, zim, vre, vim, xp[(size_t)k * D_CH]);
            __builtin_nontemporal_store(vre, &o[(size_t)k * D_CH]);
        }
    }
}

extern "C" void kernel_launch(void* const* d_in, const int* in_sizes, int n_in,
                              void* d_out, int out_size, void* d_ws, size_t ws_size,
                              hipStream_t stream) {
    const float* x  = (const float*)d_in[0];
    const float* sz = (const float*)d_in[1];
    const float* th = (const float*)d_in[2];
    float2* sums = (float2*)d_ws;                 // CC * D_CH * 8 B = 2 MB
    float* out = (float*)d_out;
    const bool realOnly = (out_size == T_LEN * D_CH);

    dim3 blk(256);
    dim3 grid(D_CH / 256, CC);                    // 1024 blocks = 4/CU

    k_sums<<<grid, blk, 0, stream>>>(x, sz, th, sums);
    if (realOnly)
        k_scan<false><<<grid, blk, 0, stream>>>(x, sz, th, sums, out);
    else
        k_scan<true><<<grid, blk, 0, stream>>>(x, sz, th, sums, out);
}